// Round 7
// baseline (1192.098 us; speedup 1.0000x reference)
//
#include <hip/hip_runtime.h>
#include <hip/hip_bf16.h>

#define BATCH 16384
#define WDIM 300
#define TDIM 100
#define TD2 200
#define HDIM 512
#define ESIZE 1024

// fp16 MFMA trilinear geometry
#define NIT 13            // i-tiles of 16: 208 = 200 real + clW row + pad
#define NJC 7             // j-chunks of 32: 224 = 200 real + pad
#define CSTR 232          // LDS C row stride (halves): 464B, 16B-mult, 2-way banks
// kC geometry
#define CVSTR 136         // cvS stride (halves): 272B = 16B-mult, 2-way banks
#define HSTR 520          // hS stride (halves): 1040B = 16B-mult, 2-way banks

typedef unsigned short ush;
typedef float f32x2 __attribute__((ext_vector_type(2)));
typedef float f32x4 __attribute__((ext_vector_type(4)));
typedef _Float16 f16x8 __attribute__((ext_vector_type(8)));
typedef _Float16 f16x4 __attribute__((ext_vector_type(4)));

__device__ __forceinline__ float bf2f(ush u) {
    union { unsigned int i; float f; } v; v.i = ((unsigned int)u) << 16; return v.f;
}
__device__ __forceinline__ float2 bf2x2(unsigned int w) {
    union { unsigned int i; float f; } a, b;
    a.i = w << 16; b.i = w & 0xffff0000u;
    return make_float2(a.f, b.f);
}
__device__ __forceinline__ ush f2bf(float f) {
    union { float f; unsigned int i; } v; v.f = f;
    unsigned int x = v.i;
    return (ush)((x + 0x7fffu + ((x >> 16) & 1u)) >> 16);
}
__device__ __forceinline__ float leaky(float v) { return v >= 0.f ? v : 0.1f * v; }

// ---------------- Kernel A3: LDS-staged, coalesced embed/projdown ----------------
__global__ __launch_bounds__(256) void kA3(const int* __restrict__ x,
                                           const float* __restrict__ eW,
                                           const float* __restrict__ pdW,
                                           const float* __restrict__ pdb,
                                           float* __restrict__ cat)
{
    __shared__ float eS[32][308];
    __shared__ float pS[20][308];
    __shared__ int idxS[32];
    const int tid = threadIdx.x;
    const int lane = tid & 63, wv = tid >> 6;
    const int b0 = blockIdx.x * 16;

    if (tid < 32) idxS[tid] = x[b0 * 2 + tid];
    __syncthreads();

    for (int r = wv; r < 32; r += 4) {
        const float4* src = (const float4*)(eW + (size_t)idxS[r] * WDIM);
        for (int d = lane; d < 75; d += 64) *(float4*)&eS[r][d * 4] = src[d];
    }

    const int r = tid >> 3, tl = tid & 7;
    const int t2ok = (tl + 16) < 20;
    const int b = b0 + (r >> 1), h = r & 1;

    for (int tc = 0; tc < 5; ++tc) {
        __syncthreads();
        for (int i = tid; i < 1500; i += 256) {
            int rr = i / 75, d = i - rr * 75;
            *(float4*)&pS[rr][d * 4] =
                *(const float4*)&pdW[(size_t)(tc * 20 + rr) * WDIM + d * 4];
        }
        __syncthreads();

        float a0 = 0.f, a1 = 0.f, a2 = 0.f;
        const int t2i = t2ok ? (tl + 16) : 0;
        for (int d = 0; d < 75; ++d) {
            float4 e4 = *(const float4*)&eS[r][d * 4];
            float4 p0 = *(const float4*)&pS[tl][d * 4];
            float4 p1 = *(const float4*)&pS[tl + 8][d * 4];
            float4 p2 = *(const float4*)&pS[t2i][d * 4];
            a0 += e4.x * p0.x + e4.y * p0.y + e4.z * p0.z + e4.w * p0.w;
            a1 += e4.x * p1.x + e4.y * p1.y + e4.z * p1.z + e4.w * p1.w;
            a2 += e4.x * p2.x + e4.y * p2.y + e4.z * p2.z + e4.w * p2.w;
        }
        {
            int t = tc * 20 + tl;
            cat[(size_t)b * TD2 + h * 100 + t] = leaky(a0 + pdb[t]);
            t += 8;
            cat[(size_t)b * TD2 + h * 100 + t] = leaky(a1 + pdb[t]);
            if (t2ok) {
                t += 8;
                cat[(size_t)b * TD2 + h * 100 + t] = leaky(a2 + pdb[t]);
            }
        }
    }
}

// ---------------- Kernel T: build fragment-ordered fp16 T' ----------------
__global__ __launch_bounds__(448) void kT(const float* __restrict__ compT,
                                          const float* __restrict__ clW,
                                          ush* __restrict__ Tp)
{
    const int k = blockIdx.x, it = blockIdx.y;
    const int jc = threadIdx.x >> 6, lane = threadIdx.x & 63;
    const int i = it * 16 + (lane & 15);
    const int j0 = jc * 32 + (lane >> 4) * 8;
    ush vals[8];
    #pragma unroll
    for (int e = 0; e < 8; ++e) {
        int j = j0 + e;
        float v = 0.f;
        if (j < 200) {
            if (i < 200) v = compT[((size_t)k * 200 + i) * 200 + j];
            else if (i == 200) v = clW[(size_t)k * 200 + j];
        }
        union { _Float16 h; ush u; } cvt; cvt.h = (_Float16)v; vals[e] = cvt.u;
    }
    size_t o = (((size_t)k * NIT + it) * NJC + jc) * 64 + lane;   // 16B units
    ((uint4*)Tp)[o] = *(const uint4*)vals;
}

// ---------------- Kernel W: convert l1W/l2W to fp16 (l1 padded K->128) ----------
__global__ __launch_bounds__(256) void kW(const float* __restrict__ l1W,
                                          const float* __restrict__ l2W,
                                          ush* __restrict__ l1p,
                                          ush* __restrict__ l2p)
{
    const int idx = blockIdx.x * 256 + threadIdx.x;
    union { _Float16 h; ush u; } cvt;
    if (idx < HDIM * 128) {
        int r = idx >> 7, c = idx & 127;
        cvt.h = (_Float16)(c < TDIM ? l1W[r * TDIM + c] : 0.f);
        l1p[idx] = cvt.u;
    } else {
        int j = idx - HDIM * 128;
        cvt.h = (_Float16)l2W[j];
        l2p[j] = cvt.u;
    }
}

// ---------------- Kernel B8: fp16 MFMA trilinear, barrier-free k-loop ----------
// grid 512 = (B/64 b-chunks) x (k-split 2), block 512 = 8 waves, 2 blocks/CU
// (LDS 29.7KB, VGPR target <=128 via __launch_bounds__(512,4) -> 16 waves/CU).
// Wave = (i-quarter q in {4,3,3,3} tiles, k-lane in {0,1}); each wave owns its
// accumulator, consumes C[b,i] via ds_read_b64 at use, reduces over rg with 2
// shuffles and writes a per-quarter partial to global part[q][k][b]. NO
// __syncthreads / atomics in the k-loop -> loads pipeline across jc AND k.
// All blocks sweep k in the same order per half -> temporal L2 sharing of the
// ~91KB/k T-window (2 windows/XCD, <<4MB). L2 traffic 2.33GB -> ~67us floor.
template<int NT>
__device__ __forceinline__ void kb8_work(const _Float16 (*__restrict__ cS)[CSTR],
                                         const ush* __restrict__ Tp,
                                         float* __restrict__ part,
                                         int t0, int q, int kq, int klane,
                                         int b0, int lane)
{
    const int cl = lane & 15, rg = lane >> 4;
    const int kbase = kq * 50;

    for (int s = 0; s < 25; ++s) {
        const int k = kbase + s * 2 + klane;
        f32x4 acc[NT][4];
        #pragma unroll
        for (int it = 0; it < NT; ++it)
            #pragma unroll
            for (int bt = 0; bt < 4; ++bt)
                acc[it][bt] = (f32x4){0.f, 0.f, 0.f, 0.f};

        #pragma unroll
        for (int jc = 0; jc < NJC; ++jc) {
            f16x8 ah[NT];
            #pragma unroll
            for (int it = 0; it < NT; ++it)
                ah[it] = *(const f16x8*)(Tp +
                    ((((size_t)k * NIT + (t0 + it)) * NJC + jc) * 64 + lane) * 8);
            f16x8 bh[4];
            #pragma unroll
            for (int bt = 0; bt < 4; ++bt)
                bh[bt] = *(const f16x8*)&cS[bt * 16 + cl][jc * 32 + rg * 8];
            #pragma unroll
            for (int it = 0; it < NT; ++it)
                #pragma unroll
                for (int bt = 0; bt < 4; ++bt)
                    acc[it][bt] = __builtin_amdgcn_mfma_f32_16x16x32_f16(
                        ah[it], bh[bt], acc[it][bt], 0, 0, 0);
        }
        // consume: v[b] = sum_i C[b,i] * D[i,b] over this quarter's i-rows
        #pragma unroll
        for (int bt = 0; bt < 4; ++bt) {
            float v = 0.f;
            #pragma unroll
            for (int it = 0; it < NT; ++it) {
                f16x4 c4 = *(const f16x4*)&cS[bt * 16 + cl][(t0 + it) * 16 + rg * 4];
                v += acc[it][bt][0] * (float)c4[0]
                   + acc[it][bt][1] * (float)c4[1]
                   + acc[it][bt][2] * (float)c4[2]
                   + acc[it][bt][3] * (float)c4[3];
            }
            v += __shfl_xor(v, 16);
            v += __shfl_xor(v, 32);
            if (lane < 16)
                part[((size_t)(q * TDIM + k) << 14) + b0 + bt * 16 + lane] = v;
        }
    }
}

__global__ __launch_bounds__(512, 4) void kB8(const float* __restrict__ cat,
                                              const ush* __restrict__ Tp,
                                              float* __restrict__ part)
{
    __shared__ _Float16 cS[64][CSTR];   // 29.7 KB
    const int tid = threadIdx.x;
    const int bid = blockIdx.x;
    const int kq = bid & 1;
    const int b0 = (bid >> 1) * 64;
    const int lane = tid & 63, w = tid >> 6;

    for (int idx = tid; idx < 64 * CSTR; idx += 512) {
        int r = idx / CSTR, c = idx - r * CSTR;
        float v = 0.f;
        if (c < 200) v = cat[(size_t)(b0 + r) * TD2 + c];
        else if (c == 200) v = 1.f;            // clW row weight
        cS[r][c] = (_Float16)v;
    }
    __syncthreads();                            // only barrier in the kernel

    const int q = w & 3, klane = w >> 2;
    if (q == 0)      kb8_work<4>(cS, Tp, part, 0,  0, kq, klane, b0, lane);
    else if (q == 1) kb8_work<3>(cS, Tp, part, 4,  1, kq, klane, b0, lane);
    else if (q == 2) kb8_work<3>(cS, Tp, part, 7,  2, kq, klane, b0, lane);
    else             kb8_work<3>(cS, Tp, part, 10, 3, kq, klane, b0, lane);
}

// ---------------- Kernel B8b: combine 4 partials + clb + leaky -> cv[k][b] ------
__global__ __launch_bounds__(256) void kB8b(const float* __restrict__ part,
                                            const float* __restrict__ clb,
                                            float* __restrict__ cv)
{
    const int idx = blockIdx.x * 256 + threadIdx.x;
    const int b = idx & (BATCH - 1);
    const int k = idx >> 14;
    float s = part[((size_t)(0 * TDIM + k) << 14) + b]
            + part[((size_t)(1 * TDIM + k) << 14) + b]
            + part[((size_t)(2 * TDIM + k) << 14) + b]
            + part[((size_t)(3 * TDIM + k) << 14) + b];
    cv[(size_t)k * BATCH + b] = leaky(s + clb[k]);
}

// ---------------- Kernel C1: cv -> h fp16 via MFMA (l1 + leaky) ----------------
__global__ __launch_bounds__(512, 2) void kC1(const float* __restrict__ cv,
                                              const ush* __restrict__ l1p,
                                              const float* __restrict__ l1b,
                                              ush* __restrict__ h)
{
    __shared__ _Float16 cvS[64][CVSTR];
    const int tid = threadIdx.x;
    const int b0 = blockIdx.x * 64;
    const int lane = tid & 63, w = tid >> 6;
    const int cl = lane & 15, rg = lane >> 4;

    for (int k0 = 0; k0 < 128; k0 += 8) {
        int k = k0 + (w);
        int bl = lane;
        float v = (k < TDIM) ? cv[(size_t)k * BATCH + b0 + bl] : 0.f;
        cvS[bl][k] = (_Float16)v;
    }
    __syncthreads();

    for (int e8 = 0; e8 < 4; ++e8) {
        const int et = w * 4 + e8;
        f32x4 acc[4];
        #pragma unroll
        for (int bt = 0; bt < 4; ++bt) acc[bt] = (f32x4){0.f, 0.f, 0.f, 0.f};
        #pragma unroll
        for (int kc = 0; kc < 4; ++kc) {
            f16x8 a = *(const f16x8*)((const _Float16*)l1p +
                       (size_t)(et * 16 + cl) * 128 + kc * 32 + rg * 8);
            #pragma unroll
            for (int bt = 0; bt < 4; ++bt) {
                f16x8 b = *(const f16x8*)&cvS[bt * 16 + cl][kc * 32 + rg * 8];
                acc[bt] = __builtin_amdgcn_mfma_f32_16x16x32_f16(a, b, acc[bt], 0, 0, 0);
            }
        }
        float4 bias = *(const float4*)&l1b[et * 16 + rg * 4];
        #pragma unroll
        for (int bt = 0; bt < 4; ++bt) {
            f16x4 hv;
            hv[0] = (_Float16)leaky(acc[bt][0] + bias.x);
            hv[1] = (_Float16)leaky(acc[bt][1] + bias.y);
            hv[2] = (_Float16)leaky(acc[bt][2] + bias.z);
            hv[3] = (_Float16)leaky(acc[bt][3] + bias.w);
            *(f16x4*)((_Float16*)h + (size_t)(b0 + bt * 16 + cl) * HDIM
                      + et * 16 + rg * 4) = hv;
        }
    }
}

// ---------------- Kernel C2: h (fp16) x l2W^T via MFMA -> out f32 + ssq --------
__global__ __launch_bounds__(512, 2) void kC2(const ush* __restrict__ h,
                                              const ush* __restrict__ l2p,
                                              const float* __restrict__ l2b,
                                              float* __restrict__ out,
                                              float* __restrict__ ssqg)
{
    __shared__ _Float16 hS[64][HSTR];
    __shared__ float ssqS[64];
    const int tid = threadIdx.x;
    const int b0 = blockIdx.x * 64;
    const int lane = tid & 63, w = tid >> 6;
    const int cl = lane & 15, rg = lane >> 4;

    for (int it = 0; it < 8; ++it) {
        int idx = it * 512 + tid;
        int row = idx >> 6, c8 = (idx & 63) * 8;
        *(uint4*)&hS[row][c8] = *(const uint4*)(h + (size_t)(b0 + row) * HDIM + c8);
    }
    if (tid < 64) ssqS[tid] = 0.f;
    __syncthreads();

    float ssqp[4] = {0.f, 0.f, 0.f, 0.f};
    for (int e8 = 0; e8 < 8; ++e8) {
        const int et = w * 8 + e8;
        f32x4 acc[4];
        #pragma unroll
        for (int bt = 0; bt < 4; ++bt) acc[bt] = (f32x4){0.f, 0.f, 0.f, 0.f};
        #pragma unroll
        for (int kc = 0; kc < 16; ++kc) {
            f16x8 a = *(const f16x8*)((const _Float16*)l2p +
                       (size_t)(et * 16 + cl) * HDIM + kc * 32 + rg * 8);
            #pragma unroll
            for (int bt = 0; bt < 4; ++bt) {
                f16x8 b = *(const f16x8*)&hS[bt * 16 + cl][kc * 32 + rg * 8];
                acc[bt] = __builtin_amdgcn_mfma_f32_16x16x32_f16(a, b, acc[bt], 0, 0, 0);
            }
        }
        float4 bias = *(const float4*)&l2b[et * 16 + rg * 4];
        #pragma unroll
        for (int bt = 0; bt < 4; ++bt) {
            float4 o;
            o.x = acc[bt][0] + bias.x;
            o.y = acc[bt][1] + bias.y;
            o.z = acc[bt][2] + bias.z;
            o.w = acc[bt][3] + bias.w;
            ssqp[bt] += o.x * o.x + o.y * o.y + o.z * o.z + o.w * o.w;
            *(float4*)&out[(size_t)(b0 + bt * 16 + cl) * ESIZE + et * 16 + rg * 4] = o;
        }
    }
    #pragma unroll
    for (int bt = 0; bt < 4; ++bt) {
        float s = ssqp[bt];
        s += __shfl_xor(s, 16);
        s += __shfl_xor(s, 32);
        if (lane < 16) atomicAdd(&ssqS[bt * 16 + lane], s);
    }
    __syncthreads();
    if (tid < 64) ssqg[b0 + tid] = ssqS[tid];
}

// ---------------- Kernel B4 (fallback): packed-f32 trilinear -> cv[k][b] -------
__global__ __launch_bounds__(512, 6) void kB4(const float* __restrict__ cat,
                                              const float* __restrict__ compT,
                                              const float* __restrict__ clW,
                                              const float* __restrict__ clb,
                                              float* __restrict__ cv)
{
    __shared__ float cS[64][201];
    const int tid = threadIdx.x;
    const int b0 = blockIdx.x * 64;
    const int lane = tid & 63;
    const int wid = tid >> 6;

    {
        int r = tid / TD2;
        int c = tid - r * TD2;
        for (int i = tid; i < 64 * TD2; i += 512) {
            cS[r][c] = cat[(size_t)(b0 + r) * TD2 + c];
            c += 112;
            if (c >= TD2) { c -= TD2; r += 3; } else { r += 2; }
        }
    }
    __syncthreads();

    int k = blockIdx.y * 8 + wid;
    if (k >= TDIM) return;
    k = __builtin_amdgcn_readfirstlane(k);

    const float* T = compT + (size_t)k * (TD2 * TD2);
    float s = 0.f;
    for (int ch = 0; ch < 4; ++ch) {
        const int c0 = ch * 50;
        f32x2 cj2[25];
        #pragma unroll
        for (int j = 0; j < 25; ++j) {
            f32x2 c2; c2.x = cS[lane][c0 + 2 * j]; c2.y = cS[lane][c0 + 2 * j + 1];
            cj2[j] = c2;
        }
        for (int i = 0; i < TD2; ++i) {
            const f32x2* T2 = (const f32x2*)(T + (size_t)i * TD2 + c0);
            f32x2 trow[25];
            #pragma unroll
            for (int j = 0; j < 25; ++j) trow[j] = T2[j];
            f32x2 u2; u2.x = 0.f; u2.y = 0.f;
            #pragma unroll
            for (int j = 0; j < 25; ++j) {
                asm("v_pk_fma_f32 %0, %1, %2, %0"
                    : "+v"(u2) : "s"(trow[j]), "v"(cj2[j]));
            }
            s += cS[lane][i] * (u2.x + u2.y);
        }
    }
    float t2 = 0.f;
    const float* W = clW + (size_t)k * TD2;
    for (int j = 0; j < TD2; ++j) t2 += W[j] * cS[lane][j];
    cv[(size_t)k * BATCH + b0 + lane] = leaky(s + t2 + clb[k]);
}

// ---------------- Kernel Cf (fallback): f32 l1+l2 path, reads cv[k][b] ---------
__global__ __launch_bounds__(256) void kCf(const float* __restrict__ cv,
                                           const float* __restrict__ l1W,
                                           const float* __restrict__ l1b,
                                           const float* __restrict__ l2W,
                                           const float* __restrict__ l2b,
                                           float* __restrict__ out,
                                           float* __restrict__ ssqg)
{
    __shared__ ush hS[32 * 528];
    __shared__ float w2F[8 * 516];
    const int tid = threadIdx.x;
    const int b0 = blockIdx.x * 32;

    float* cvS = w2F;
    for (int i = tid; i < 3200; i += 256) {
        int k = i >> 5, bl = i & 31;
        cvS[bl * TDIM + k] = cv[(size_t)k * BATCH + b0 + bl];
    }
    __syncthreads();
    for (int o = tid; o < 32 * HDIM; o += 256) {
        int bl = o & 31, e = o >> 5;
        const float* cr = &cvS[bl * TDIM];
        const float* wr = &l1W[e * TDIM];
        float s = 0.f;
        for (int t = 0; t < TDIM; t += 4) {
            float4 w4 = *(const float4*)&wr[t];
            float4 c4 = *(const float4*)&cr[t];
            s += w4.x * c4.x + w4.y * c4.y + w4.z * c4.z + w4.w * c4.w;
        }
        s = leaky(s + l1b[e]);
        hS[bl * 528 + e] = f2bf(s);
    }
    __syncthreads();

    const int b = tid >> 3, el = tid & 7;
    float ssq = 0.f;
    for (int ec = 0; ec < 128; ++ec) {
        {
            const float* src = l2W + (size_t)ec * 8 * HDIM;
            for (int i = tid; i < 1024; i += 256) {
                int r = i >> 7, c4 = (i & 127) * 4;
                *(float4*)&w2F[r * 516 + c4] = *(const float4*)&src[r * HDIM + c4];
            }
        }
        __syncthreads();
        {
            const ush* hr = &hS[b * 528];
            const float* wr2 = &w2F[el * 516];
            float s = 0.f;
            for (int j = 0; j < HDIM; j += 8) {
                uint4 hv = *(const uint4*)&hr[j];
                float4 w0 = *(const float4*)&wr2[j];
                float4 w1 = *(const float4*)&wr2[j + 4];
                float2 h0 = bf2x2(hv.x), h1 = bf2x2(hv.y), h2 = bf2x2(hv.z), h3 = bf2x2(hv.w);
                s += h0.x * w0.x + h0.y * w0.y + h1.x * w0.z + h1.y * w0.w
                   + h2.x * w1.x + h2.y * w1.y + h3.x * w1.z + h3.y * w1.w;
            }
            int eg = ec * 8 + el;
            float v = s + l2b[eg];
            out[(size_t)(b0 + b) * ESIZE + eg] = v;
            ssq += v * v;
        }
        __syncthreads();
    }
    ssq += __shfl_xor(ssq, 1);
    ssq += __shfl_xor(ssq, 2);
    ssq += __shfl_xor(ssq, 4);
    if (el == 0) ssqg[b0 + b] = ssq;
}

// ---------------- Kernel D: normalize f32 rows in place ----------------
__global__ __launch_bounds__(256) void kD(float* __restrict__ out,
                                          const float* __restrict__ ssqg)
{
    const int tid = threadIdx.x;
    const int row = blockIdx.x * 2 + (tid >> 7);
    const int col = (tid & 127) * 8;
    const float r = rsqrtf(ssqg[row]);
    float* p = out + (size_t)row * ESIZE + col;
    float4 v0 = *(float4*)p;
    float4 v1 = *(float4*)(p + 4);
    v0.x *= r; v0.y *= r; v0.z *= r; v0.w *= r;
    v1.x *= r; v1.y *= r; v1.z *= r; v1.w *= r;
    *(float4*)p = v0;
    *(float4*)(p + 4) = v1;
}

extern "C" void kernel_launch(void* const* d_in, const int* in_sizes, int n_in,
                              void* d_out, int out_size, void* d_ws, size_t ws_size,
                              hipStream_t stream) {
    const int*   x    = (const int*)d_in[0];
    const float* eW   = (const float*)d_in[2];
    const float* pdW  = (const float*)d_in[3];
    const float* pdb  = (const float*)d_in[4];
    const float* cT   = (const float*)d_in[5];
    const float* clW  = (const float*)d_in[6];
    const float* clb  = (const float*)d_in[7];
    const float* l1W  = (const float*)d_in[8];
    const float* l1b  = (const float*)d_in[9];
    const float* l2W  = (const float*)d_in[10];
    const float* l2b  = (const float*)d_in[11];
    float* out = (float*)d_out;

    // workspace layout (all segments 16B-aligned by construction)
    const size_t catN = (size_t)BATCH * TD2;                 // f32
    const size_t cvN  = (size_t)BATCH * TDIM;                // f32
    const size_t ssqN = (size_t)BATCH;                       // f32
    const size_t partN = (size_t)4 * TDIM * BATCH;           // f32
    const size_t tpN  = (size_t)TDIM * NIT * NJC * 64 * 8;   // ush
    const size_t l1pN = (size_t)HDIM * 128;                  // ush
    const size_t l2pN = (size_t)ESIZE * HDIM;                // ush
    const size_t hN   = (size_t)BATCH * HDIM;                // ush

    float* cat  = (float*)d_ws;
    float* cv   = cat + catN;
    float* ssqg = cv + cvN;
    float* part = ssqg + ssqN;
    ush*   Tp   = (ush*)(part + partN);
    ush*   l1p  = Tp + tpN;
    ush*   l2p  = l1p + l1pN;
    ush*   hbuf = l2p + l2pN;

    const size_t need = (catN + cvN + ssqN + partN) * 4 + (tpN + l1pN + l2pN + hN) * 2;

    kA3<<<dim3(BATCH / 16), dim3(256), 0, stream>>>(x, eW, pdW, pdb, cat);
    if (ws_size >= need) {
        kT  <<<dim3(TDIM, NIT), dim3(448), 0, stream>>>(cT, clW, Tp);
        kW  <<<dim3((HDIM * 128 + ESIZE * HDIM) / 256), dim3(256), 0, stream>>>(l1W, l2W, l1p, l2p);
        kB8 <<<dim3(BATCH / 64 * 2), dim3(512), 0, stream>>>(cat, Tp, part);
        kB8b<<<dim3(BATCH * TDIM / 256), dim3(256), 0, stream>>>(part, clb, cv);
        kC1 <<<dim3(BATCH / 64), dim3(512), 0, stream>>>(cv, l1p, l1b, hbuf);
        kC2 <<<dim3(BATCH / 64), dim3(512), 0, stream>>>(hbuf, l2p, l2b, out, ssqg);
    } else {
        kB4<<<dim3(BATCH / 64, 13), dim3(512), 0, stream>>>(cat, cT, clW, clb, cv);
        kCf<<<dim3(512), dim3(256), 0, stream>>>(cv, l1W, l1b, l2W, l2b, out, ssqg);
    }
    kD<<<dim3(8192), dim3(256), 0, stream>>>(out, ssqg);
}